// Round 6
// baseline (3107.354 us; speedup 1.0000x reference)
//
#include <hip/hip_runtime.h>
#include <math.h>

#define N_NODES 100000
#define EMB 64
#define N_EDGES 1200000
#define N_ELEM (N_NODES * EMB)   // 6,400,000

// ---------------------------------------------------------------------------
// Threefry-2x32, 20 rounds — exact JAX semantics (jax._src.prng.threefry2x32)
// ---------------------------------------------------------------------------
__device__ __forceinline__ unsigned rotl32(unsigned v, int r) {
    return (v << r) | (v >> (32 - r));
}

__device__ __forceinline__ void threefry2x32(unsigned k0, unsigned k1,
                                             unsigned c0, unsigned c1,
                                             unsigned& o0, unsigned& o1) {
    const unsigned ks0 = k0;
    const unsigned ks1 = k1;
    const unsigned ks2 = k0 ^ k1 ^ 0x1BD11BDAu;
    unsigned x0 = c0 + ks0;
    unsigned x1 = c1 + ks1;
#define TF_RND(r) { x0 += x1; x1 = rotl32(x1, r); x1 ^= x0; }
    TF_RND(13) TF_RND(15) TF_RND(26) TF_RND(6)
    x0 += ks1; x1 += ks2 + 1u;
    TF_RND(17) TF_RND(29) TF_RND(16) TF_RND(24)
    x0 += ks2; x1 += ks0 + 2u;
    TF_RND(13) TF_RND(15) TF_RND(26) TF_RND(6)
    x0 += ks0; x1 += ks1 + 3u;
    TF_RND(17) TF_RND(29) TF_RND(16) TF_RND(24)
    x0 += ks1; x1 += ks2 + 4u;
    TF_RND(13) TF_RND(15) TF_RND(26) TF_RND(6)
    x0 += ks2; x1 += ks0 + 5u;
#undef TF_RND
    o0 = x0;
    o1 = x1;
}

// ---------------------------------------------------------------------------
// Kernels (propagation identical to Round 4 — known to run end-to-end)
// ---------------------------------------------------------------------------
__global__ void k_degree(const int* __restrict__ dst, float* __restrict__ deg) {
    int e = blockIdx.x * blockDim.x + threadIdx.x;
    if (e < N_EDGES) atomicAdd(&deg[dst[e]], 1.0f);
}

__global__ void k_dis(float* __restrict__ deg) {
    int i = blockIdx.x * blockDim.x + threadIdx.x;
    if (i < N_NODES) {
        float d = deg[i];
        deg[i] = (d > 0.0f) ? rsqrtf(d) : 0.0f;   // deg>=1 when >0, matches max(deg,1)
    }
}

__global__ void k_norm(const int* __restrict__ src, const int* __restrict__ dst,
                       const float* __restrict__ dis, float* __restrict__ norm) {
    int e = blockIdx.x * blockDim.x + threadIdx.x;
    if (e < N_EDGES) norm[e] = dis[src[e]] * dis[dst[e]];
}

// One edge handled by 16 threads; each thread: one float4 gather + 4 atomics.
__global__ void k_prop(const int* __restrict__ src, const int* __restrict__ dst,
                       const float* __restrict__ norm,
                       const float* __restrict__ x, float* __restrict__ y) {
    int t = blockIdx.x * blockDim.x + threadIdx.x;
    int e = t >> 4;
    if (e >= N_EDGES) return;
    int c = (t & 15) << 2;
    int s = src[e];
    int d = dst[e];
    float nm = norm[e];
    const float4 v = *reinterpret_cast<const float4*>(x + (size_t)s * EMB + c);
    float* yp = y + (size_t)d * EMB + c;
    atomicAdd(yp + 0, v.x * nm);
    atomicAdd(yp + 1, v.y * nm);
    atomicAdd(yp + 2, v.z * nm);
    atomicAdd(yp + 3, v.w * nm);
}

// acc = a + b
__global__ void k_acc_init(float* __restrict__ acc, const float* __restrict__ a,
                           const float* __restrict__ b) {
    int i = blockIdx.x * blockDim.x + threadIdx.x;
    if (i < N_ELEM) acc[i] = a[i] + b[i];
}

// acc += a
__global__ void k_acc_add(float* __restrict__ acc, const float* __restrict__ a) {
    int i = blockIdx.x * blockDim.x + threadIdx.x;
    if (i < N_ELEM) acc[i] += a[i];
}

// out = dropout(acc / 4), PARTITIONABLE threefry (JAX >= 0.4.36 default):
// per flat element i: counts = iota(uint64) -> pair (0, uint32(i));
// bits = o0 ^ o1 (32-bit combiner); u = bitcast((bits>>9)|0x3f800000) - 1;
// keep iff u < 0.9f.
__global__ void k_dropout(float* __restrict__ out) {
    int i = blockIdx.x * blockDim.x + threadIdx.x;
    if (i >= N_ELEM) return;
    unsigned o0, o1;
    threefry2x32(0u, 42u, 0u, (unsigned)i, o0, o1);
    unsigned bits = o0 ^ o1;
    float u = __uint_as_float((bits >> 9) | 0x3f800000u) - 1.0f;
    float a = out[i];
    out[i] = (u < 0.9f) ? ((a * 0.25f) / 0.9f) : 0.0f;
}

// ---------------------------------------------------------------------------
// Launch
// ---------------------------------------------------------------------------
extern "C" void kernel_launch(void* const* d_in, const int* in_sizes, int n_in,
                              void* d_out, int out_size, void* d_ws, size_t ws_size,
                              hipStream_t stream) {
    const float* emb = (const float*)d_in[0];
    const int* eidx = (const int*)d_in[1];
    const int* src = eidx;             // edge_index[0]
    const int* dst = eidx + N_EDGES;   // edge_index[1]
    float* acc = (float*)d_out;

    // workspace layout (floats): deg 100k | norm 1.2M | bufA 6.4M | bufB 6.4M
    float* ws = (float*)d_ws;
    float* deg  = ws;
    float* norm = ws + 100000;
    float* bufA = ws + 1300000;
    float* bufB = ws + 7700000;        // total 56.4 MB

    const int BLK = 256;
    const int gE    = (N_EDGES + BLK - 1) / BLK;
    const int gN    = (N_NODES + BLK - 1) / BLK;
    const int gElem = (N_ELEM + BLK - 1) / BLK;
    const int gProp = (N_EDGES * 16) / BLK;

    // degree + norm
    hipMemsetAsync(deg, 0, N_NODES * sizeof(float), stream);
    k_degree<<<gE, BLK, 0, stream>>>(dst, deg);
    k_dis<<<gN, BLK, 0, stream>>>(deg);
    k_norm<<<gE, BLK, 0, stream>>>(src, dst, deg, norm);

    // layer 1: emb -> bufB ; acc = emb + bufB
    hipMemsetAsync(bufB, 0, N_ELEM * sizeof(float), stream);
    k_prop<<<gProp, BLK, 0, stream>>>(src, dst, norm, emb, bufB);
    k_acc_init<<<gElem, BLK, 0, stream>>>(acc, emb, bufB);

    // layer 2: bufB -> bufA ; acc += bufA
    hipMemsetAsync(bufA, 0, N_ELEM * sizeof(float), stream);
    k_prop<<<gProp, BLK, 0, stream>>>(src, dst, norm, bufB, bufA);
    k_acc_add<<<gElem, BLK, 0, stream>>>(acc, bufA);

    // layer 3: bufA -> bufB ; acc += bufB
    hipMemsetAsync(bufB, 0, N_ELEM * sizeof(float), stream);
    k_prop<<<gProp, BLK, 0, stream>>>(src, dst, norm, bufA, bufB);
    k_acc_add<<<gElem, BLK, 0, stream>>>(acc, bufB);

    // final: acc/4 with partitionable-threefry dropout
    k_dropout<<<gElem, BLK, 0, stream>>>(acc);
}

// Round 7
// 518.522 us; speedup vs baseline: 5.9927x; 5.9927x over previous
//
#include <hip/hip_runtime.h>
#include <math.h>

#define N_NODES 100000
#define EMB 64
#define N_EDGES 1200000
#define N_ELEM (N_NODES * EMB)   // 6,400,000

// ---------------------------------------------------------------------------
// Threefry-2x32, 20 rounds — exact JAX semantics, PARTITIONABLE mode
// (verified passing in Round 6).
// ---------------------------------------------------------------------------
__device__ __forceinline__ unsigned rotl32(unsigned v, int r) {
    return (v << r) | (v >> (32 - r));
}

__device__ __forceinline__ void threefry2x32(unsigned k0, unsigned k1,
                                             unsigned c0, unsigned c1,
                                             unsigned& o0, unsigned& o1) {
    const unsigned ks0 = k0;
    const unsigned ks1 = k1;
    const unsigned ks2 = k0 ^ k1 ^ 0x1BD11BDAu;
    unsigned x0 = c0 + ks0;
    unsigned x1 = c1 + ks1;
#define TF_RND(r) { x0 += x1; x1 = rotl32(x1, r); x1 ^= x0; }
    TF_RND(13) TF_RND(15) TF_RND(26) TF_RND(6)
    x0 += ks1; x1 += ks2 + 1u;
    TF_RND(17) TF_RND(29) TF_RND(16) TF_RND(24)
    x0 += ks2; x1 += ks0 + 2u;
    TF_RND(13) TF_RND(15) TF_RND(26) TF_RND(6)
    x0 += ks0; x1 += ks1 + 3u;
    TF_RND(17) TF_RND(29) TF_RND(16) TF_RND(24)
    x0 += ks1; x1 += ks2 + 4u;
    TF_RND(13) TF_RND(15) TF_RND(26) TF_RND(6)
    x0 += ks2; x1 += ks0 + 5u;
#undef TF_RND
    o0 = x0;
    o1 = x1;
}

// keep-decision for flat element i (bernoulli 0.9, key (0,42), partitionable):
__device__ __forceinline__ bool drop_keep(unsigned i) {
    unsigned o0, o1;
    threefry2x32(0u, 42u, 0u, i, o0, o1);
    unsigned bits = o0 ^ o1;
    float u = __uint_as_float((bits >> 9) | 0x3f800000u) - 1.0f;
    return u < 0.9f;
}

// ---------------------------------------------------------------------------
// CSR construction
// ---------------------------------------------------------------------------
__global__ void k_hist(const int* __restrict__ dst, int* __restrict__ cnt) {
    int e = blockIdx.x * blockDim.x + threadIdx.x;
    if (e < N_EDGES) atomicAdd(&cnt[dst[e]], 1);
}

__global__ void k_dis(const int* __restrict__ cnt, float* __restrict__ dis) {
    int i = blockIdx.x * blockDim.x + threadIdx.x;
    if (i < N_NODES) {
        int d = cnt[i];
        dis[i] = (d > 0) ? rsqrtf((float)d) : 0.0f;
    }
}

// Single-block exclusive scan of cnt[0..N_NODES) -> rowptr & cursor.
__global__ void k_scan(const int* __restrict__ cnt, int* __restrict__ rowptr,
                       int* __restrict__ cursor) {
    __shared__ int wsum[16];
    const int tid = threadIdx.x;
    const int lane = tid & 63;
    const int wid = tid >> 6;
    int carry = 0;
    for (int base = 0; base < N_NODES; base += 1024) {
        int i = base + tid;
        int v = (i < N_NODES) ? cnt[i] : 0;
        int x = v;
#pragma unroll
        for (int off = 1; off < 64; off <<= 1) {
            int t = __shfl_up(x, off, 64);
            if (lane >= off) x += t;
        }
        if (lane == 63) wsum[wid] = x;
        __syncthreads();
        if (wid == 0 && lane < 16) {
            int w = wsum[lane];
#pragma unroll
            for (int off = 1; off < 16; off <<= 1) {
                int t = __shfl_up(w, off, 64);
                if (lane >= off) w += t;
            }
            wsum[lane] = w;  // inclusive scan of wave totals
        }
        __syncthreads();
        int wexc = (wid == 0) ? 0 : wsum[wid - 1];
        int exc = carry + (x + wexc) - v;
        if (i < N_NODES) { rowptr[i] = exc; cursor[i] = exc; }
        carry += wsum[15];
        __syncthreads();
    }
    if (tid == 0) rowptr[N_NODES] = carry;
}

__global__ void k_scatter(const int* __restrict__ src, const int* __restrict__ dst,
                          const float* __restrict__ dis, int* __restrict__ cursor,
                          int* __restrict__ src_sorted, float* __restrict__ norm_sorted) {
    int e = blockIdx.x * blockDim.x + threadIdx.x;
    if (e >= N_EDGES) return;
    int s = src[e];
    int d = dst[e];
    int pos = atomicAdd(&cursor[d], 1);
    src_sorted[pos] = s;
    norm_sorted[pos] = dis[s] * dis[d];
}

// ---------------------------------------------------------------------------
// Propagation: one wave64 per node, lane = dim. Gather-only, no atomics.
// MODE 0 (layer 1): y = sum; acc = x(own) + sum       (x == emb)
// MODE 1 (layer 2): y = sum; acc += sum
// MODE 2 (layer 3): total = acc + sum; acc = dropout(total/4)  [no y write]
// ---------------------------------------------------------------------------
template <int MODE>
__global__ void k_agg(const int* __restrict__ rowptr, const int* __restrict__ src_sorted,
                      const float* __restrict__ norm_sorted,
                      const float* __restrict__ x, float* __restrict__ y,
                      float* __restrict__ acc) {
    int wave = (blockIdx.x * blockDim.x + threadIdx.x) >> 6;
    int lane = threadIdx.x & 63;
    if (wave >= N_NODES) return;
    int begin = rowptr[wave];
    int end = rowptr[wave + 1];
    float sum = 0.0f;
    int j = begin;
    for (; j + 1 < end; j += 2) {          // unroll-by-2 for load ILP
        int s0 = src_sorted[j];
        int s1 = src_sorted[j + 1];
        float n0 = norm_sorted[j];
        float n1 = norm_sorted[j + 1];
        float v0 = x[(size_t)s0 * EMB + lane];
        float v1 = x[(size_t)s1 * EMB + lane];
        sum += v0 * n0 + v1 * n1;
    }
    if (j < end) {
        int s0 = src_sorted[j];
        sum += x[(size_t)s0 * EMB + lane] * norm_sorted[j];
    }
    size_t idx = (size_t)wave * EMB + lane;
    if (MODE == 0) {
        y[idx] = sum;
        acc[idx] = x[idx] + sum;
    } else if (MODE == 1) {
        y[idx] = sum;
        acc[idx] += sum;
    } else {
        float total = acc[idx] + sum;
        bool keep = drop_keep((unsigned)idx);
        acc[idx] = keep ? ((total * 0.25f) / 0.9f) : 0.0f;
    }
}

// ---------------------------------------------------------------------------
// Launch
// ---------------------------------------------------------------------------
extern "C" void kernel_launch(void* const* d_in, const int* in_sizes, int n_in,
                              void* d_out, int out_size, void* d_ws, size_t ws_size,
                              hipStream_t stream) {
    const float* emb = (const float*)d_in[0];
    const int* eidx = (const int*)d_in[1];
    const int* src = eidx;             // edge_index[0]
    const int* dst = eidx + N_EDGES;   // edge_index[1]
    float* acc = (float*)d_out;

    // workspace layout (4B elems), total ~62 MB
    char* ws = (char*)d_ws;
    int*   cnt         = (int*)ws;                    // 100,000
    int*   rowptr      = (int*)(ws + 400000);         // 100,001
    int*   cursor      = (int*)(ws + 800004);         // 100,000
    float* dis         = (float*)(ws + 1200004);      // 100,000
    int*   src_sorted  = (int*)(ws + 1600004);        // 1,200,000
    float* norm_sorted = (float*)(ws + 6400004);      // 1,200,000
    float* bufA        = (float*)(ws + 11200004);     // 6,400,000
    float* bufB        = (float*)(ws + 36800004);     // 6,400,000

    const int BLK = 256;
    const int gE   = (N_EDGES + BLK - 1) / BLK;
    const int gN   = (N_NODES + BLK - 1) / BLK;
    const int gAgg = (N_NODES * 64 + BLK - 1) / BLK;  // 1 wave64 per node

    // CSR build
    hipMemsetAsync(cnt, 0, N_NODES * sizeof(int), stream);
    k_hist<<<gE, BLK, 0, stream>>>(dst, cnt);
    k_dis<<<gN, BLK, 0, stream>>>(cnt, dis);
    k_scan<<<1, 1024, 0, stream>>>(cnt, rowptr, cursor);
    k_scatter<<<gE, BLK, 0, stream>>>(src, dst, dis, cursor, src_sorted, norm_sorted);

    // 3 gather-only propagation layers; acc and final dropout fused
    k_agg<0><<<gAgg, BLK, 0, stream>>>(rowptr, src_sorted, norm_sorted, emb,  bufA, acc);
    k_agg<1><<<gAgg, BLK, 0, stream>>>(rowptr, src_sorted, norm_sorted, bufA, bufB, acc);
    k_agg<2><<<gAgg, BLK, 0, stream>>>(rowptr, src_sorted, norm_sorted, bufB, nullptr, acc);
}

// Round 9
// 378.003 us; speedup vs baseline: 8.2205x; 1.3717x over previous
//
#include <hip/hip_runtime.h>
#include <math.h>

#define N_NODES 100000
#define EMB 64
#define N_EDGES 1200000
#define N_ELEM (N_NODES * EMB)   // 6,400,000
#define SCAN_CHUNK 1024
#define SCAN_NBLK ((N_NODES + SCAN_CHUNK - 1) / SCAN_CHUNK)   // 98

// ---------------------------------------------------------------------------
// Threefry-2x32, 20 rounds — JAX partitionable mode (verified R6/R7)
// ---------------------------------------------------------------------------
__device__ __forceinline__ unsigned rotl32(unsigned v, int r) {
    return (v << r) | (v >> (32 - r));
}

__device__ __forceinline__ void threefry2x32(unsigned k0, unsigned k1,
                                             unsigned c0, unsigned c1,
                                             unsigned& o0, unsigned& o1) {
    const unsigned ks0 = k0;
    const unsigned ks1 = k1;
    const unsigned ks2 = k0 ^ k1 ^ 0x1BD11BDAu;
    unsigned x0 = c0 + ks0;
    unsigned x1 = c1 + ks1;
#define TF_RND(r) { x0 += x1; x1 = rotl32(x1, r); x1 ^= x0; }
    TF_RND(13) TF_RND(15) TF_RND(26) TF_RND(6)
    x0 += ks1; x1 += ks2 + 1u;
    TF_RND(17) TF_RND(29) TF_RND(16) TF_RND(24)
    x0 += ks2; x1 += ks0 + 2u;
    TF_RND(13) TF_RND(15) TF_RND(26) TF_RND(6)
    x0 += ks0; x1 += ks1 + 3u;
    TF_RND(17) TF_RND(29) TF_RND(16) TF_RND(24)
    x0 += ks1; x1 += ks2 + 4u;
    TF_RND(13) TF_RND(15) TF_RND(26) TF_RND(6)
    x0 += ks2; x1 += ks0 + 5u;
#undef TF_RND
    o0 = x0;
    o1 = x1;
}

__device__ __forceinline__ bool drop_keep(unsigned i) {
    unsigned o0, o1;
    threefry2x32(0u, 42u, 0u, i, o0, o1);
    unsigned bits = o0 ^ o1;
    float u = __uint_as_float((bits >> 9) | 0x3f800000u) - 1.0f;
    return u < 0.9f;
}

// ---------------------------------------------------------------------------
// CSR construction
// ---------------------------------------------------------------------------
__global__ void k_hist(const int* __restrict__ dst, int* __restrict__ cnt) {
    int e = blockIdx.x * blockDim.x + threadIdx.x;
    if (e < N_EDGES) atomicAdd(&cnt[dst[e]], 1);
}

// pass 1: per-1024-chunk local exclusive scan (into `local`), chunk totals,
// fused dis[] computation.
__global__ void k_scan1(const int* __restrict__ cnt, int* __restrict__ local,
                        int* __restrict__ bsum, float* __restrict__ dis) {
    __shared__ int wsum[16];
    const int tid = threadIdx.x;
    const int lane = tid & 63;
    const int wid = tid >> 6;
    int i = blockIdx.x * SCAN_CHUNK + tid;
    int v = (i < N_NODES) ? cnt[i] : 0;
    if (i < N_NODES) dis[i] = (v > 0) ? rsqrtf((float)v) : 0.0f;
    int x = v;
#pragma unroll
    for (int off = 1; off < 64; off <<= 1) {
        int t = __shfl_up(x, off, 64);
        if (lane >= off) x += t;
    }
    if (lane == 63) wsum[wid] = x;
    __syncthreads();
    if (wid == 0 && lane < 16) {
        int w = wsum[lane];
#pragma unroll
        for (int off = 1; off < 16; off <<= 1) {
            int t = __shfl_up(w, off, 64);
            if (lane >= off) w += t;
        }
        wsum[lane] = w;   // inclusive scan of wave totals
    }
    __syncthreads();
    int wexc = (wid == 0) ? 0 : wsum[wid - 1];
    if (i < N_NODES) local[i] = (x + wexc) - v;   // exclusive within chunk
    if (tid == 0) bsum[blockIdx.x] = wsum[15];    // chunk total
}

// pass 2: exclusive scan of the 98 chunk totals (single 128-thread block)
__global__ void k_scan2(const int* __restrict__ bsum, int* __restrict__ bofs) {
    __shared__ int sh[128];
    int t = threadIdx.x;
    int v = (t < SCAN_NBLK) ? bsum[t] : 0;
    sh[t] = v;
    __syncthreads();
    for (int off = 1; off < 128; off <<= 1) {
        int add = (t >= off) ? sh[t - off] : 0;
        __syncthreads();
        sh[t] += add;
        __syncthreads();
    }
    if (t < SCAN_NBLK) bofs[t] = sh[t] - v;   // exclusive
}

// pass 3: rowptr/cursor = local + chunk offset. local aliases cursor (i->i map).
__global__ void k_scan3(int* __restrict__ cursor_local, const int* __restrict__ bofs,
                        int* __restrict__ rowptr) {
    int i = blockIdx.x * SCAN_CHUNK + threadIdx.x;
    if (i < N_NODES) {
        int r = cursor_local[i] + bofs[blockIdx.x];
        rowptr[i] = r;
        cursor_local[i] = r;
    }
    if (i == 0) rowptr[N_NODES] = N_EDGES;
}

// edges packed as int2{src, bitcast(norm)}
__global__ void k_scatter(const int* __restrict__ src, const int* __restrict__ dst,
                          const float* __restrict__ dis, int* __restrict__ cursor,
                          int2* __restrict__ edges) {
    int e = blockIdx.x * blockDim.x + threadIdx.x;
    if (e >= N_EDGES) return;
    int s = src[e];
    int d = dst[e];
    int pos = atomicAdd(&cursor[d], 1);
    edges[pos] = make_int2(s, __float_as_int(dis[s] * dis[d]));
}

// ---------------------------------------------------------------------------
// Propagation: one wave64 per node; 4 groups of 16 lanes; lane = float4 of dims.
// Each loop iteration gathers 4 rows (1 KB) per wave -> 4x MLP vs R7.
// MODE 0: y = sum; acc = x(own) + sum
// MODE 1: y = sum; acc += sum
// MODE 2: acc = dropout((acc + sum)/4)   [no y write]
// ---------------------------------------------------------------------------
template <int MODE>
__global__ void k_agg(const int* __restrict__ rowptr, const int2* __restrict__ edges,
                      const float* __restrict__ x, float* __restrict__ y,
                      float* __restrict__ acc) {
    int wv = (blockIdx.x * blockDim.x + threadIdx.x) >> 6;
    if (wv >= N_NODES) return;
    const int lane = threadIdx.x & 63;
    const int g = lane >> 4;       // group 0..3
    const int l16 = lane & 15;     // lane within group: dims 4*l16 .. 4*l16+3
    const int begin = rowptr[wv];
    const int end = rowptr[wv + 1];
    float4 s = make_float4(0.f, 0.f, 0.f, 0.f);
    const float* xb = x + (size_t)(l16 << 2);
    for (int j = begin + g; j < end; j += 4) {
        int2 rec = edges[j];
        float nm = __int_as_float(rec.y);
        const float4 v = *reinterpret_cast<const float4*>(xb + (size_t)rec.x * EMB);
        s.x += v.x * nm; s.y += v.y * nm; s.z += v.z * nm; s.w += v.w * nm;
    }
    // reduce across the 4 groups (lane bits 4,5)
    s.x += __shfl_xor(s.x, 16, 64); s.y += __shfl_xor(s.y, 16, 64);
    s.z += __shfl_xor(s.z, 16, 64); s.w += __shfl_xor(s.w, 16, 64);
    s.x += __shfl_xor(s.x, 32, 64); s.y += __shfl_xor(s.y, 32, 64);
    s.z += __shfl_xor(s.z, 32, 64); s.w += __shfl_xor(s.w, 32, 64);

    const size_t ridx = (size_t)wv * EMB + (l16 << 2);
    if (MODE == 0) {
        if (g == 0) *reinterpret_cast<float4*>(y + ridx) = s;
        if (g == 1) {
            float4 own = *reinterpret_cast<const float4*>(x + ridx);
            *reinterpret_cast<float4*>(acc + ridx) =
                make_float4(own.x + s.x, own.y + s.y, own.z + s.z, own.w + s.w);
        }
    } else if (MODE == 1) {
        if (g == 0) *reinterpret_cast<float4*>(y + ridx) = s;
        if (g == 1) {
            float4 a = *reinterpret_cast<const float4*>(acc + ridx);
            *reinterpret_cast<float4*>(acc + ridx) =
                make_float4(a.x + s.x, a.y + s.y, a.z + s.z, a.w + s.w);
        }
    } else {
        // spread threefry over all 64 lanes: lane (g,l16) evaluates element 4*l16+g
        unsigned rowbase = (unsigned)((size_t)wv * EMB);
        bool k = drop_keep(rowbase + (unsigned)((l16 << 2) + g));
        unsigned long long mask = __ballot(k);
        if (g == 0) {
            float4 a = *reinterpret_cast<const float4*>(acc + ridx);
            float4 t = make_float4(a.x + s.x, a.y + s.y, a.z + s.z, a.w + s.w);
            const float sc = 0.25f / 0.9f;
            float4 o;
            o.x = ((mask >> (0 * 16 + l16)) & 1ull) ? t.x * sc : 0.f;
            o.y = ((mask >> (1 * 16 + l16)) & 1ull) ? t.y * sc : 0.f;
            o.z = ((mask >> (2 * 16 + l16)) & 1ull) ? t.z * sc : 0.f;
            o.w = ((mask >> (3 * 16 + l16)) & 1ull) ? t.w * sc : 0.f;
            *reinterpret_cast<float4*>(acc + ridx) = o;
        }
    }
}

// ---------------------------------------------------------------------------
// Launch
// ---------------------------------------------------------------------------
extern "C" void kernel_launch(void* const* d_in, const int* in_sizes, int n_in,
                              void* d_out, int out_size, void* d_ws, size_t ws_size,
                              hipStream_t stream) {
    const float* emb = (const float*)d_in[0];
    const int* eidx = (const int*)d_in[1];
    const int* src = eidx;             // edge_index[0]
    const int* dst = eidx + N_EDGES;   // edge_index[1]
    float* acc = (float*)d_out;

    // workspace layout (bytes; bufA/bufB 16B-aligned)
    char* ws = (char*)d_ws;
    int*   cnt     = (int*)(ws + 0);           // 100,000 ints
    int*   cursor  = (int*)(ws + 400000);      // 100,000 ints (aliases scan `local`)
    int*   bsum    = (int*)(ws + 800000);      // 98
    int*   bofs    = (int*)(ws + 800400);      // 98
    int*   rowptr  = (int*)(ws + 800800);      // 100,001
    float* dis     = (float*)(ws + 1200808);   // 100,000
    int2*  edges   = (int2*)(ws + 1600808);    // 1,200,000 int2 (8B-aligned)
    float* bufA    = (float*)(ws + 11200816);  // 6,400,000 (16B-aligned)
    float* bufB    = (float*)(ws + 36800816);  // 6,400,000; end ~62.4 MB

    const int BLK = 256;
    const int gE   = (N_EDGES + BLK - 1) / BLK;
    const int gAgg = (N_NODES * 64 + BLK - 1) / BLK;   // 1 wave64 per node

    // CSR build
    hipMemsetAsync(cnt, 0, N_NODES * sizeof(int), stream);
    k_hist<<<gE, BLK, 0, stream>>>(dst, cnt);
    k_scan1<<<SCAN_NBLK, SCAN_CHUNK, 0, stream>>>(cnt, cursor, bsum, dis);
    k_scan2<<<1, 128, 0, stream>>>(bsum, bofs);
    k_scan3<<<SCAN_NBLK, SCAN_CHUNK, 0, stream>>>(cursor, bofs, rowptr);
    k_scatter<<<gE, BLK, 0, stream>>>(src, dst, dis, cursor, edges);

    // 3 gather-only propagation layers; acc and final dropout fused
    k_agg<0><<<gAgg, BLK, 0, stream>>>(rowptr, edges, emb,  bufA, acc);
    k_agg<1><<<gAgg, BLK, 0, stream>>>(rowptr, edges, bufA, bufB, acc);
    k_agg<2><<<gAgg, BLK, 0, stream>>>(rowptr, edges, bufB, nullptr, acc);
}